// Round 1
// baseline (212.892 us; speedup 1.0000x reference)
//
#include <hip/hip_runtime.h>

// CubePadding: input x [B,6,C,H,W] fp32 -> output [B,6,C,H+2P,W+2P] fp32.
// Every output element is a copy of one input element. Memory-bound.
// Face order (dim 1): 0=back(fb) 1=down(fd) 2=front(ff) 3=left(fl) 4=right(fr) 5=top(ft)

constexpr int P = 2, B = 4, C = 64, H = 128, W = 128;
constexpr int Ho = H + 2 * P, Wo = W + 2 * P;
constexpr int TOTAL = B * 6 * C * Ho * Wo;   // 26,763,264

// ---- halo source maps, derived from the JAX reference ----
// top strip [t in 0..P), w in [0..W)
__device__ __forceinline__ void top_map(int f, int t, int w, int& sf, int& r, int& col) {
    switch (f) {
        case 0:  sf = 5; r = P - 1 - t; col = w;         break;  // flip_h(ft[:P])
        case 1:  sf = 2; r = H - P + t; col = w;         break;  // ff[-P:]
        case 2:  sf = 5; r = H - P + t; col = w;         break;  // ft[-P:]
        case 3:  sf = 5; r = w;         col = t;         break;  // T(ft[:,:P])
        case 4:  sf = 5; r = w;         col = W - 1 - t; break;  // flip_h(T(ft[:,-P:]))
        default: sf = 0; r = P - 1 - t; col = w;         break;  // flip_h(fb[:P])
    }
}
// bottom strip [t in 0..P), w in [0..W)
__device__ __forceinline__ void bot_map(int f, int t, int w, int& sf, int& r, int& col) {
    switch (f) {
        case 0:  sf = 1; r = H - 1 - t; col = w;         break;  // flip_h(fd[-P:])
        case 1:  sf = 0; r = H - 1 - t; col = w;         break;  // flip_h(fb[-P:])
        case 2:  sf = 1; r = t;         col = w;         break;  // fd[:P]
        case 3:  sf = 1; r = w;         col = P - 1 - t; break;  // flip_h(T(fd[:,:P]))
        case 4:  sf = 1; r = w;         col = W - P + t; break;  // T(fd[:,-P:])
        default: sf = 2; r = t;         col = w;         break;  // ff[:P]
    }
}
// left strip [h in 0..H), l in [0..P)
__device__ __forceinline__ void lft_map(int f, int h, int l, int& sf, int& r, int& col) {
    switch (f) {
        case 0:  sf = 4; r = h;         col = W - P + l; break;  // fr[:,-P:]
        case 1:  sf = 3; r = H - 1 - l; col = h;         break;  // flip_w(T(fl[-P:]))
        case 2:  sf = 3; r = h;         col = W - P + l; break;  // fl[:,-P:]
        case 3:  sf = 0; r = h;         col = W - P + l; break;  // fb[:,-P:]
        case 4:  sf = 2; r = h;         col = W - P + l; break;  // ff[:,-P:]
        default: sf = 3; r = l;         col = h;         break;  // T(fl[:P])
    }
}
// right strip [h in 0..H), rr in [0..P)
__device__ __forceinline__ void rgt_map(int f, int h, int rr, int& sf, int& r, int& col) {
    switch (f) {
        case 0:  sf = 3; r = h;          col = rr;        break;  // fl[:,:P]
        case 1:  sf = 4; r = H - P + rr; col = h;         break;  // T(fr[-P:])
        case 2:  sf = 4; r = h;          col = rr;        break;  // fr[:,:P]
        case 3:  sf = 2; r = h;          col = rr;        break;  // ff[:,:P]
        case 4:  sf = 0; r = h;          col = rr;        break;  // fb[:,:P]
        default: sf = 4; r = P - 1 - rr; col = h;         break;  // flip_w(T(fr[:P]))
    }
}

__global__ __launch_bounds__(256) void cubepad_kernel(const float* __restrict__ x,
                                                      float* __restrict__ out) {
    int idx = blockIdx.x * 256 + threadIdx.x;
    if (idx >= TOTAL) return;

    int j    = idx % Wo;
    int t1   = idx / Wo;
    int i    = t1 % Ho;
    int rest = t1 / Ho;          // (b*6 + f)*C + c
    int c    = rest % C;
    int bf   = rest / C;         // b*6 + f
    int f    = bf % 6;
    int b    = bf / 6;

    bool in_h = (i >= P) && (i < H + P);
    bool in_w = (j >= P) && (j < W + P);

    int sf, r, col;
    if (in_h && in_w) {
        // interior: identity copy (94% of elements, fully coalesced)
        sf = f; r = i - P; col = j - P;
    } else if (!in_h) {
        // top/bottom strips; corners replicate the strip's edge column
        int w = in_w ? (j - P) : (j < P ? 0 : W - 1);
        if (i < P) top_map(f, i, w, sf, r, col);
        else       bot_map(f, i - H - P, w, sf, r, col);
    } else {
        if (j < P) lft_map(f, i - P, j,         sf, r, col);
        else       rgt_map(f, i - P, j - W - P, sf, r, col);
    }

    size_t src = (size_t)((b * 6 + sf) * C + c) * (H * W) + (size_t)r * W + col;
    out[idx] = x[src];
}

extern "C" void kernel_launch(void* const* d_in, const int* in_sizes, int n_in,
                              void* d_out, int out_size, void* d_ws, size_t ws_size,
                              hipStream_t stream) {
    const float* x = (const float*)d_in[0];
    float* out = (float*)d_out;
    int blocks = (TOTAL + 255) / 256;
    cubepad_kernel<<<blocks, 256, 0, stream>>>(x, out);
}

// Round 2
// 183.812 us; speedup vs baseline: 1.1582x; 1.1582x over previous
//
#include <hip/hip_runtime.h>

// CubePadding: x [B,6,C,H,W] fp32 -> out [B,6,C,H+2P,W+2P] fp32. Pure gather/copy.
// R1: one thread per output float4 (Wo=132 = 33 aligned float4/row).
//     Interior fast path: 2x aligned float2 loads + 1x float4 store.
//     Edge groups (~9%) take a per-element gather path.
// Face order: 0=back(fb) 1=down(fd) 2=front(ff) 3=left(fl) 4=right(fr) 5=top(ft)

constexpr int P = 2, B = 4, C = 64, H = 128, W = 128;
constexpr int Ho = H + 2 * P, Wo = W + 2 * P;
constexpr int NV = Wo / 4;                    // 33 float4 groups per row
constexpr int TOTAL_V = B * 6 * C * Ho * NV;  // 6,690,816 threads

// ---- halo source maps (verified in R0) ----
__device__ __forceinline__ void top_map(int f, int t, int w, int& sf, int& r, int& col) {
    switch (f) {
        case 0:  sf = 5; r = P - 1 - t; col = w;         break;
        case 1:  sf = 2; r = H - P + t; col = w;         break;
        case 2:  sf = 5; r = H - P + t; col = w;         break;
        case 3:  sf = 5; r = w;         col = t;         break;
        case 4:  sf = 5; r = w;         col = W - 1 - t; break;
        default: sf = 0; r = P - 1 - t; col = w;         break;
    }
}
__device__ __forceinline__ void bot_map(int f, int t, int w, int& sf, int& r, int& col) {
    switch (f) {
        case 0:  sf = 1; r = H - 1 - t; col = w;         break;
        case 1:  sf = 0; r = H - 1 - t; col = w;         break;
        case 2:  sf = 1; r = t;         col = w;         break;
        case 3:  sf = 1; r = w;         col = P - 1 - t; break;
        case 4:  sf = 1; r = w;         col = W - P + t; break;
        default: sf = 2; r = t;         col = w;         break;
    }
}
__device__ __forceinline__ void lft_map(int f, int h, int l, int& sf, int& r, int& col) {
    switch (f) {
        case 0:  sf = 4; r = h;         col = W - P + l; break;
        case 1:  sf = 3; r = H - 1 - l; col = h;         break;
        case 2:  sf = 3; r = h;         col = W - P + l; break;
        case 3:  sf = 0; r = h;         col = W - P + l; break;
        case 4:  sf = 2; r = h;         col = W - P + l; break;
        default: sf = 3; r = l;         col = h;         break;
    }
}
__device__ __forceinline__ void rgt_map(int f, int h, int rr, int& sf, int& r, int& col) {
    switch (f) {
        case 0:  sf = 3; r = h;          col = rr;        break;
        case 1:  sf = 4; r = H - P + rr; col = h;         break;
        case 2:  sf = 4; r = h;          col = rr;        break;
        case 3:  sf = 2; r = h;          col = rr;        break;
        case 4:  sf = 0; r = h;          col = rr;        break;
        default: sf = 4; r = P - 1 - rr; col = h;         break;
    }
}

// general per-element map: output (f,i,j) -> source (sf,r,col) within the same batch
__device__ __forceinline__ void gen_map(int f, int i, int j, int& sf, int& r, int& col) {
    bool in_h = (i >= P) && (i < H + P);
    bool in_w = (j >= P) && (j < W + P);
    if (in_h && in_w) {
        sf = f; r = i - P; col = j - P;
    } else if (!in_h) {
        int w = in_w ? (j - P) : (j < P ? 0 : W - 1);   // corners replicate strip edge
        if (i < P) top_map(f, i, w, sf, r, col);
        else       bot_map(f, i - H - P, w, sf, r, col);
    } else {
        if (j < P) lft_map(f, i - P, j,         sf, r, col);
        else       rgt_map(f, i - P, j - W - P, sf, r, col);
    }
}

__global__ __launch_bounds__(256) void cubepad_v4_kernel(const float* __restrict__ x,
                                                         float* __restrict__ out) {
    int idx = blockIdx.x * 256 + threadIdx.x;
    if (idx >= TOTAL_V) return;

    int v    = idx % NV;          // float4 group within row: out cols [4v, 4v+4)
    int t1   = idx / NV;
    int i    = t1 % Ho;
    int rest = t1 / Ho;           // (b*6 + f)*C + c
    int f    = (rest / C) % 6;
    int bC   = (rest / (C * 6)) * 6 * C + (rest % C);  // b*6*C + c  (for src plane base)

    float4 val;
    float* vp = (float*)&val;
    size_t out_off = (size_t)t1 * Wo + 4 * v;

    bool fast = (i >= P) && (i < H + P) && (v >= 1) && (v < NV - 1);
    if (fast) {
        // src: face f, row i-P, cols 4v-2 .. 4v+1 (8B-aligned start)
        const float* src = x + ((size_t)(bC + f * C)) * (H * W)
                             + (size_t)(i - P) * W + (4 * v - P);
        float2 lo = *(const float2*)(src);
        float2 hi = *(const float2*)(src + 2);
        val = make_float4(lo.x, lo.y, hi.x, hi.y);
    } else {
        #pragma unroll
        for (int e = 0; e < 4; ++e) {
            int sf, r, col;
            gen_map(f, i, 4 * v + e, sf, r, col);
            vp[e] = x[((size_t)(bC + sf * C)) * (H * W) + (size_t)r * W + col];
        }
    }
    *(float4*)(out + out_off) = val;
}

extern "C" void kernel_launch(void* const* d_in, const int* in_sizes, int n_in,
                              void* d_out, int out_size, void* d_ws, size_t ws_size,
                              hipStream_t stream) {
    const float* x = (const float*)d_in[0];
    float* out = (float*)d_out;
    int blocks = (TOTAL_V + 255) / 256;
    cubepad_v4_kernel<<<blocks, 256, 0, stream>>>(x, out);
}